// Round 8
// baseline (488.481 us; speedup 1.0000x reference)
//
#include <hip/hip_runtime.h>

#define ALPHA 0.9f
#define BETA  0.8f
#define K     25
#define B     128
#define T     16
#define IN_DIM 14400
#define NSL   4      // batch slices of width 32; XCD pair (2e,2e+1) shares slice e
#define SW    32     // slice width (batch elems) -> 128B rows, fully used per instr

// ---------------------------------------------------------------------------
// Slice-pinned persistent transpose: x (B,T,IN) slab [t0,t0+8) ->
// xTh[8t][4s][IN][32]. blockIdx%8 = XCD; XCD (2s+h) handles slice s, i-half h.
// Tiles 32i x 32b, one pass per side, LDS 32x33.
// ---------------------------------------------------------------------------
__global__ __launch_bounds__(256, 4) void transpose_p(
    const float* __restrict__ x, float* __restrict__ xTh, int t0, int slots) {
  __shared__ float tile[32][33];
  const int xcd  = blockIdx.x & 7;
  const int s    = xcd >> 1;         // slice 0..3
  const int hh   = xcd & 1;          // i-half
  const int slot = blockIdx.x >> 3;
  const int r    = threadIdx.x >> 3;   // 0..31: b-row (read) / i-row (write)
  const int q    = threadIdx.x & 7;    // quad index

  const int NTILES = 8 * 225;          // 8 local t x (7200/32) i-tiles
  for (int tix = slot; tix < NTILES; tix += slots) {
    const int tl = tix / 225;
    const int i0 = (tix % 225) * 32;
    const int t  = t0 + tl;
    const int gi = hh * 7200 + i0;
    // read: 32 b-rows x 32 i (8 lanes x 16B = 128B per row)
    {
      const int b = s * 32 + r;
      const float4 v =
          *(const float4*)&x[((size_t)b * T + t) * IN_DIM + gi + q * 4];
      tile[r][q * 4 + 0] = v.x;
      tile[r][q * 4 + 1] = v.y;
      tile[r][q * 4 + 2] = v.z;
      tile[r][q * 4 + 3] = v.w;
    }
    __syncthreads();
    // write: 32 i-rows x 32 b (contiguous 128B per i-row)
    {
      float4 v;
      v.x = tile[q * 4 + 0][r];
      v.y = tile[q * 4 + 1][r];
      v.z = tile[q * 4 + 2][r];
      v.w = tile[q * 4 + 3][r];
      *(float4*)&xTh[(((size_t)tl * NSL + s) * IN_DIM + (gi + r)) * SW +
                     q * 4] = v;
    }
    __syncthreads();
  }
}

// ---------------------------------------------------------------------------
// LCN+LIF layer, SW=32 rows. hsrc: [nt][4][dprev][32], memout: [nt][4][dim][32],
// state: [2][4][dim][32]. blockIdx%8 = XCD; XCD (2s+nh) processes slice s,
// neuron half nh -> each 128B source row is resident in exactly 2 L2s and
// every wave-instr covers 8 fully-used 128B rows (half the request count of
// SW=16). One neuron-group per block, t-inner, idx/w hoisted once.
// K-loop in explicit 8/8/9 load-then-FMA chunks for deep per-wave MLP
// (launch_bounds cap 128 VGPR; 4 blk/CU x 256 = 1024 residency >= all grids).
// ---------------------------------------------------------------------------
template <int NT>
__global__ __launch_bounds__(256, 4) void lcn_sw32(
    const float* __restrict__ hsrc, const float* __restrict__ w,
    const float* __restrict__ bias, const int* __restrict__ knn,
    float* __restrict__ memout, float* __restrict__ state,
    int dim, int dprev, int load_state, int save_state) {
  const int xcd = blockIdx.x & 7;
  const int s   = xcd >> 1;            // slice
  const int nh  = xcd & 1;             // neuron half
  const int g   = blockIdx.x >> 3;     // group within half
  const int npb = blockDim.x >> 3;     // neurons per block (32 or 8)
  const int nl  = threadIdx.x >> 3;    // neuron in group
  const int bq  = (threadIdx.x & 7) * 4;  // batch quad within slice
  const int dimh = dim >> 1;
  const int ldn  = g * npb + nl;
  const bool act = ldn < dimh;
  const int d    = nh * dimh + (act ? ldn : dimh - 1);

  int   idx[K];
  float wr[K];
#pragma unroll
  for (int k = 0; k < K; ++k) {
    idx[k] = knn[d * K + k] * SW + bq;
    wr[k]  = w[d * K + k];
  }
  const float bi = bias[d];

  float4 sy = make_float4(0.f, 0.f, 0.f, 0.f);
  float4 me = make_float4(0.f, 0.f, 0.f, 0.f);
  if (load_state) {
    const size_t so = ((size_t)s * dim + d) * SW + bq;
    sy = *(const float4*)&state[so];
    me = *(const float4*)&state[(size_t)NSL * dim * SW + so];
  }

  for (int t = 0; t < NT; ++t) {
    const float* hp = hsrc + ((size_t)t * NSL + s) * dprev * SW;
    float4 a0 = make_float4(bi, bi, bi, bi);
    float4 a1 = make_float4(0.f, 0.f, 0.f, 0.f);
    // chunks k=0..7, 8..15 (two accumulators, loads batched before FMAs)
#pragma unroll
    for (int c = 0; c < 2; ++c) {
      float4 hv[8];
#pragma unroll
      for (int j = 0; j < 8; ++j)
        hv[j] = *(const float4*)&hp[idx[c * 8 + j]];
#pragma unroll
      for (int j = 0; j < 8; ++j) {
        const float wk = wr[c * 8 + j];
        if (j & 1) {
          a1.x = fmaf(wk, hv[j].x, a1.x);
          a1.y = fmaf(wk, hv[j].y, a1.y);
          a1.z = fmaf(wk, hv[j].z, a1.z);
          a1.w = fmaf(wk, hv[j].w, a1.w);
        } else {
          a0.x = fmaf(wk, hv[j].x, a0.x);
          a0.y = fmaf(wk, hv[j].y, a0.y);
          a0.z = fmaf(wk, hv[j].z, a0.z);
          a0.w = fmaf(wk, hv[j].w, a0.w);
        }
      }
    }
    {  // tail k=16..24
      float4 hv[9];
#pragma unroll
      for (int j = 0; j < 9; ++j)
        hv[j] = *(const float4*)&hp[idx[16 + j]];
#pragma unroll
      for (int j = 0; j < 9; ++j) {
        const float wk = wr[16 + j];
        if (j & 1) {
          a1.x = fmaf(wk, hv[j].x, a1.x);
          a1.y = fmaf(wk, hv[j].y, a1.y);
          a1.z = fmaf(wk, hv[j].z, a1.z);
          a1.w = fmaf(wk, hv[j].w, a1.w);
        } else {
          a0.x = fmaf(wk, hv[j].x, a0.x);
          a0.y = fmaf(wk, hv[j].y, a0.y);
          a0.z = fmaf(wk, hv[j].z, a0.z);
          a0.w = fmaf(wk, hv[j].w, a0.w);
        }
      }
    }
    const float4 acc = make_float4(a0.x + a1.x, a0.y + a1.y, a0.z + a1.z,
                                   a0.w + a1.w);
    sy.x = ALPHA * sy.x + acc.x;
    sy.y = ALPHA * sy.y + acc.y;
    sy.z = ALPHA * sy.z + acc.z;
    sy.w = ALPHA * sy.w + acc.w;
    float4 r;
    r.x = (me.x > 1.0f) ? 1.0f : 0.0f;  // reset from PREVIOUS membrane
    r.y = (me.y > 1.0f) ? 1.0f : 0.0f;
    r.z = (me.z > 1.0f) ? 1.0f : 0.0f;
    r.w = (me.w > 1.0f) ? 1.0f : 0.0f;
    me.x = BETA * me.x + sy.x - r.x;
    me.y = BETA * me.y + sy.y - r.y;
    me.z = BETA * me.z + sy.z - r.z;
    me.w = BETA * me.w + sy.w - r.w;
    if (act) {
      *(float4*)&memout[(((size_t)t * NSL + s) * dim + d) * SW + bq] = me;
    }
  }

  if (save_state && act) {
    const size_t so = ((size_t)s * dim + d) * SW + bq;
    *(float4*)&state[so] = sy;
    *(float4*)&state[(size_t)NSL * dim * SW + so] = me;
  }
}

// Final FC on last timestep's layer-4 membrane: m4 = [4][450][32].
__global__ __launch_bounds__(128) void fc_kernel(
    const float* __restrict__ m4, const float* __restrict__ fc_w,
    const float* __restrict__ fc_b, float* __restrict__ out) {
  const int b  = threadIdx.x;
  const int s  = b >> 5;
  const int bl = b & 31;
  float a0 = fc_b[0], a1 = fc_b[1];
  for (int d = 0; d < 450; ++d) {
    const float h = m4[((size_t)s * 450 + d) * SW + bl];
    a0 += fc_w[d] * h;
    a1 += fc_w[450 + d] * h;
  }
  out[b * 2 + 0] = a0;
  out[b * 2 + 1] = a1;
}

extern "C" void kernel_launch(void* const* d_in, const int* in_sizes, int n_in,
                              void* d_out, int out_size, void* d_ws,
                              size_t ws_size, hipStream_t stream) {
  (void)in_sizes; (void)n_in; (void)out_size; (void)ws_size;
  const float* x = (const float*)d_in[0];
  const float* w[5];
  const float* bias[5];
  const int* knn[5];
  for (int i = 0; i < 5; ++i) {
    w[i]    = (const float*)d_in[1 + 3 * i];
    bias[i] = (const float*)d_in[2 + 3 * i];
    knn[i]  = (const int*)d_in[3 + 3 * i];
  }
  const float* fc_w = (const float*)d_in[16];
  const float* fc_b = (const float*)d_in[17];
  float* out = (float*)d_out;

  static const int DIMS[5] = {7200, 3600, 1800, 900, 450};

  // Workspace (floats), 125.3 MB, slice-major [t][4][d][32]:
  //   A  : 16*4*7200*32 = 14,745,600   (mem0 -> mem2 -> mem4)
  //   XB : 8*4*14400*32 = 14,745,600   (xT half-slab; later mem1 + mem3)
  //   S  : 2*4*7200*32  =  1,843,200   (layer-0 syn/mem carry)
  float* A  = (float*)d_ws;
  float* XB = A + 14745600;
  float* S  = XB + 14745600;

  float* mem0 = A;
  float* mem1 = XB;
  float* mem2 = A;
  float* mem3 = XB + 7372800;
  float* mem4 = A;

  // ---- Layer 0 in two 8-t stages (xT half-slab reuse) ----
  for (int stage = 0; stage < 2; ++stage) {
    const int t0 = stage * 8;
    transpose_p<<<128 * 8, 256, 0, stream>>>(x, XB, t0, 128);
    const int ng = (DIMS[0] / 2 + 31) / 32;  // 113
    lcn_sw32<8><<<ng * 8, 256, 0, stream>>>(
        XB, w[0], bias[0], knn[0], mem0 + (size_t)t0 * NSL * DIMS[0] * SW, S,
        DIMS[0], IN_DIM, /*load=*/stage, /*save=*/stage == 0);
  }

  // ---- Layers 1..4, all 16 timesteps ----
  //   L1: 256-thr blocks (npb=32); L2..L4: 64-thr blocks (npb=8) for more
  //   blocks -> more CUs active on the small layers.
  const float* src = mem0;
  float* dsts[4] = {mem1, mem2, mem3, mem4};
  for (int i = 1; i < 5; ++i) {
    const int thr = (i == 1) ? 256 : 64;
    const int npb = thr >> 3;
    const int ng  = (DIMS[i] / 2 + npb - 1) / npb;
    lcn_sw32<16><<<ng * 8, thr, 0, stream>>>(
        src, w[i], bias[i], knn[i], dsts[i - 1], nullptr, DIMS[i],
        DIMS[i - 1], 0, 0);
    src = dsts[i - 1];
  }

  fc_kernel<<<1, 128, 0, stream>>>(mem4 + (size_t)15 * NSL * DIMS[4] * SW,
                                   fc_w, fc_b, out);
}

// Round 9
// 420.940 us; speedup vs baseline: 1.1605x; 1.1605x over previous
//
#include <hip/hip_runtime.h>

#define ALPHA 0.9f
#define BETA  0.8f
#define K     25
#define B     128
#define T     16
#define IN_DIM 14400
#define NSL   8      // batch slices (= XCDs)
#define SW    16     // slice width (batch elems)
#define NPG   32     // neurons per pre-tile (128 thr = 32 n x 4 quads)

// ---------------------------------------------------------------------------
// Transpose one 8-t slab of x (B,T,IN) -> xTh[8t][8e][IN][16] (slice-major).
// Proven round 6/7.
// ---------------------------------------------------------------------------
__global__ __launch_bounds__(256) void transpose_x4_kernel(
    const float* __restrict__ x, float* __restrict__ xTh, int t0) {
  __shared__ float tile[64][65];
  const int tl = blockIdx.z;            // local t 0..7
  const int t  = t0 + tl;
  const int i0 = blockIdx.x * 64;       // feature tile
  const int b0 = blockIdx.y * 64;       // batch tile
  const int tid = threadIdx.x;

  const int fi = (tid & 15) * 4;        // feature quad
  const int bi = tid >> 4;              // batch row 0..15
#pragma unroll
  for (int p = 0; p < 4; ++p) {
    const int b = bi + p * 16;
    const float4 v = *(const float4*)&x[(size_t)(b0 + b) * (T * IN_DIM) +
                                        (size_t)t * IN_DIM + i0 + fi];
    tile[fi + 0][b] = v.x;
    tile[fi + 1][b] = v.y;
    tile[fi + 2][b] = v.z;
    tile[fi + 3][b] = v.w;
  }
  __syncthreads();
  const int bq = (tid & 15) * 4;        // batch quad (0,4,..,60)
  const int fr = tid >> 4;              // feature row 0..15
  const int e  = (b0 + bq) >> 4;        // slice
  const int bl = bq & 15;               // 0,4,8,12
#pragma unroll
  for (int p = 0; p < 4; ++p) {
    const int f = fr + p * 16;
    float4 v;
    v.x = tile[f][bq + 0];
    v.y = tile[f][bq + 1];
    v.z = tile[f][bq + 2];
    v.w = tile[f][bq + 3];
    *(float4*)&xTh[(((size_t)tl * NSL + e) * IN_DIM + (i0 + f)) * SW + bl] = v;
  }
}

// ---------------------------------------------------------------------------
// PRE kernel: pre[t][e][d][16] = bias[d] + sum_k w[d][k]*h[t][e][knn[d][k]][:].
// All (t,d) independent -> massive wave parallelism (the LIF recurrence is
// split out). Persistent slice-pinned blocks: grid = 8 x slots <= residency
// so blockIdx%8 == XCD exactly, forever. Tiles (t,g) iterated t-MAJOR so all
// co-resident blocks work the same 1-2 t-slices (per-XCD L2 working set
// ~1-2 MB + knn/w). 128 thr = 32 neurons x 4 batch-quads; float4 gathers.
// ---------------------------------------------------------------------------
__global__ __launch_bounds__(128, 8) void lcn_pre(
    const float* __restrict__ hsrc, const float* __restrict__ w,
    const float* __restrict__ bias, const int* __restrict__ knn,
    float* __restrict__ pre, int dim, int dprev, int ntiles, int slots,
    int ng) {
  const int e    = blockIdx.x & 7;       // slice -> XCD
  const int slot = blockIdx.x >> 3;
  const int nl   = threadIdx.x >> 2;     // neuron in tile (0..31)
  const int bq   = (threadIdx.x & 3) * 4;

  for (int tile = slot; tile < ntiles; tile += slots) {
    const int t  = tile / ng;            // t-major ordering
    const int g  = tile - t * ng;
    const int dd = g * NPG + nl;
    const bool act = dd < dim;
    const int d  = act ? dd : dim - 1;
    const int* kp   = knn + d * K;
    const float* wp = w + d * K;
    const float* hp = hsrc + ((size_t)t * NSL + e) * dprev * SW;

    float4 a0 = make_float4(bias[d], bias[d], bias[d], bias[d]);
    float4 a1 = make_float4(0.f, 0.f, 0.f, 0.f);
#pragma unroll
    for (int c = 0; c < 2; ++c) {
      float4 hv[8];
#pragma unroll
      for (int j = 0; j < 8; ++j)
        hv[j] = *(const float4*)&hp[kp[c * 8 + j] * SW + bq];
#pragma unroll
      for (int j = 0; j < 8; ++j) {
        const float wk = wp[c * 8 + j];
        if (j & 1) {
          a1.x = fmaf(wk, hv[j].x, a1.x);
          a1.y = fmaf(wk, hv[j].y, a1.y);
          a1.z = fmaf(wk, hv[j].z, a1.z);
          a1.w = fmaf(wk, hv[j].w, a1.w);
        } else {
          a0.x = fmaf(wk, hv[j].x, a0.x);
          a0.y = fmaf(wk, hv[j].y, a0.y);
          a0.z = fmaf(wk, hv[j].z, a0.z);
          a0.w = fmaf(wk, hv[j].w, a0.w);
        }
      }
    }
    {  // tail k=16..24
      float4 hv[9];
#pragma unroll
      for (int j = 0; j < 9; ++j)
        hv[j] = *(const float4*)&hp[kp[16 + j] * SW + bq];
#pragma unroll
      for (int j = 0; j < 9; ++j) {
        const float wk = wp[16 + j];
        if (j & 1) {
          a1.x = fmaf(wk, hv[j].x, a1.x);
          a1.y = fmaf(wk, hv[j].y, a1.y);
          a1.z = fmaf(wk, hv[j].z, a1.z);
          a1.w = fmaf(wk, hv[j].w, a1.w);
        } else {
          a0.x = fmaf(wk, hv[j].x, a0.x);
          a0.y = fmaf(wk, hv[j].y, a0.y);
          a0.z = fmaf(wk, hv[j].z, a0.z);
          a0.w = fmaf(wk, hv[j].w, a0.w);
        }
      }
    }
    if (act) {
      const float4 acc = make_float4(a0.x + a1.x, a0.y + a1.y, a0.z + a1.z,
                                     a0.w + a1.w);
      *(float4*)&pre[(((size_t)t * NSL + e) * dim + d) * SW + bq] = acc;
    }
  }
}

// ---------------------------------------------------------------------------
// LIF kernel: in-place pre -> mem over the trace [nt][8][dim][16].
// Thread = one (e,d,bl); loops t (coalesced streaming, stride nt*8*dim*16/..).
// blockIdx%8 = slice so reads hit the XCD-local L2 where pre was just written.
// ---------------------------------------------------------------------------
__global__ __launch_bounds__(256) void lif_inplace(
    float* __restrict__ trace, float* __restrict__ state, int dim, int nt,
    int load_state, int save_state) {
  const int e  = blockIdx.x & 7;
  const int j  = blockIdx.x >> 3;
  const int el = j * 256 + threadIdx.x;   // element within slice
  const int sz = dim * SW;
  if (el >= sz) return;
  float* p = trace + (size_t)e * sz + el;
  const size_t tstride = (size_t)NSL * sz;

  float s = 0.f, m = 0.f;
  const size_t so = (size_t)e * sz + el;
  if (load_state) {
    s = state[so];
    m = state[tstride + so];  // tstride == NSL*dim*SW == state plane size
  }
  for (int t = 0; t < nt; ++t) {
    const float pre = p[(size_t)t * tstride];
    s = ALPHA * s + pre;
    const float r = (m > 1.0f) ? 1.0f : 0.0f;  // reset from PREVIOUS membrane
    m = BETA * m + s - r;
    p[(size_t)t * tstride] = m;
  }
  if (save_state) {
    state[so] = s;
    state[tstride + so] = m;
  }
}

// Final FC on last timestep's layer-4 membrane: mem4_t15 [8][450][16].
__global__ __launch_bounds__(128) void fc_kernel(
    const float* __restrict__ mem4_t15, const float* __restrict__ fc_w,
    const float* __restrict__ fc_b, float* __restrict__ out) {
  const int b  = threadIdx.x;
  const int e  = b >> 4;
  const int bl = b & 15;
  float a0 = fc_b[0], a1 = fc_b[1];
  for (int d = 0; d < 450; ++d) {
    const float h = mem4_t15[((size_t)e * 450 + d) * SW + bl];
    a0 += fc_w[d] * h;
    a1 += fc_w[450 + d] * h;
  }
  out[b * 2 + 0] = a0;
  out[b * 2 + 1] = a1;
}

static void launch_pre(const float* src, const float* w, const float* b,
                       const int* knn, float* pre, int dim, int dprev, int nt,
                       hipStream_t stream) {
  const int ng     = (dim + NPG - 1) / NPG;
  const int ntiles = nt * ng;
  const int slots  = ntiles < 512 ? ntiles : 512;  // grid <= 4096 = residency
  lcn_pre<<<slots * NSL, 128, 0, stream>>>(src, w, b, knn, pre, dim, dprev,
                                           ntiles, slots, ng);
}

static void launch_lif(float* trace, float* state, int dim, int nt, int ld,
                       int sv, hipStream_t stream) {
  const int nj = (dim * SW + 255) / 256;
  lif_inplace<<<nj * NSL, 256, 0, stream>>>(trace, state, dim, nt, ld, sv);
}

extern "C" void kernel_launch(void* const* d_in, const int* in_sizes, int n_in,
                              void* d_out, int out_size, void* d_ws,
                              size_t ws_size, hipStream_t stream) {
  (void)in_sizes; (void)n_in; (void)out_size; (void)ws_size;
  const float* x = (const float*)d_in[0];
  const float* w[5];
  const float* bias[5];
  const int* knn[5];
  for (int i = 0; i < 5; ++i) {
    w[i]    = (const float*)d_in[1 + 3 * i];
    bias[i] = (const float*)d_in[2 + 3 * i];
    knn[i]  = (const int*)d_in[3 + 3 * i];
  }
  const float* fc_w = (const float*)d_in[16];
  const float* fc_b = (const float*)d_in[17];
  float* out = (float*)d_out;

  static const int DIMS[5] = {7200, 3600, 1800, 900, 450};

  // Workspace (floats), 125.3 MB, slice-major [t][8][d][16]:
  //   A  : 16*8*7200*16 = 14,745,600   (mem0 -> pre2/mem2 -> pre4/mem4)
  //   XB : 8*8*14400*16 = 14,745,600   (xT half-slab; later mem1 + mem3)
  //   S  : 2*8*7200*16  =  1,843,200   (layer-0 syn/mem carry)
  float* A  = (float*)d_ws;
  float* XB = A + 14745600;
  float* S  = XB + 14745600;

  float* mem0 = A;                 // [16][8][7200][16]
  float* mem1 = XB;                // [16][8][3600][16] (xT dead)
  float* mem2 = A;                 // [16][8][1800][16] (mem0 dead)
  float* mem3 = XB + 7372800;      // [16][8][900][16]
  float* mem4 = A;                 // [16][8][450][16]  (mem2 dead)

  // ---- Layer 0 in two 8-t stages (xT half-slab reuse) ----
  for (int stage = 0; stage < 2; ++stage) {
    const int t0 = stage * 8;
    transpose_x4_kernel<<<dim3(IN_DIM / 64, B / 64, 8), 256, 0, stream>>>(
        x, XB, t0);
    float* slab = mem0 + (size_t)t0 * NSL * DIMS[0] * SW;
    launch_pre(XB, w[0], bias[0], knn[0], slab, DIMS[0], IN_DIM, 8, stream);
    launch_lif(slab, S, DIMS[0], 8, /*load=*/stage, /*save=*/stage == 0,
               stream);
  }

  // ---- Layers 1..4, all 16 timesteps ----
  const float* src = mem0;
  float* dsts[4] = {mem1, mem2, mem3, mem4};
  for (int i = 1; i < 5; ++i) {
    launch_pre(src, w[i], bias[i], knn[i], dsts[i - 1], DIMS[i], DIMS[i - 1],
               16, stream);
    launch_lif(dsts[i - 1], nullptr, DIMS[i], 16, 0, 0, stream);
    src = dsts[i - 1];
  }

  fc_kernel<<<1, 128, 0, stream>>>(mem4 + (size_t)15 * NSL * DIMS[4] * SW,
                                   fc_w, fc_b, out);
}

// Round 10
// 402.250 us; speedup vs baseline: 1.2144x; 1.0465x over previous
//
#include <hip/hip_runtime.h>

#define ALPHA 0.9f
#define BETA  0.8f
#define K     25
#define B     128
#define T     16
#define IN_DIM 14400
#define NSL   8      // batch slices (= XCDs)
#define SW    16     // slice width (batch elems)
#define NPG   32     // neurons per group (128 thr = 32 n x 4 quads)

// ---------------------------------------------------------------------------
// Transpose one 8-t slab of x (B,T,IN) -> xTh[8t][8e][IN][16] (slice-major).
// Proven rounds 6-7.
// ---------------------------------------------------------------------------
__global__ __launch_bounds__(256) void transpose_x4_kernel(
    const float* __restrict__ x, float* __restrict__ xTh, int t0) {
  __shared__ float tile[64][65];
  const int tl = blockIdx.z;            // local t 0..7
  const int t  = t0 + tl;
  const int i0 = blockIdx.x * 64;       // feature tile
  const int b0 = blockIdx.y * 64;       // batch tile
  const int tid = threadIdx.x;

  const int fi = (tid & 15) * 4;        // feature quad
  const int bi = tid >> 4;              // batch row 0..15
#pragma unroll
  for (int p = 0; p < 4; ++p) {
    const int b = bi + p * 16;
    const float4 v = *(const float4*)&x[(size_t)(b0 + b) * (T * IN_DIM) +
                                        (size_t)t * IN_DIM + i0 + fi];
    tile[fi + 0][b] = v.x;
    tile[fi + 1][b] = v.y;
    tile[fi + 2][b] = v.z;
    tile[fi + 3][b] = v.w;
  }
  __syncthreads();
  const int bq = (tid & 15) * 4;        // batch quad (0,4,..,60)
  const int fr = tid >> 4;              // feature row 0..15
  const int e  = (b0 + bq) >> 4;        // slice
  const int bl = bq & 15;               // 0,4,8,12
#pragma unroll
  for (int p = 0; p < 4; ++p) {
    const int f = fr + p * 16;
    float4 v;
    v.x = tile[f][bq + 0];
    v.y = tile[f][bq + 1];
    v.z = tile[f][bq + 2];
    v.w = tile[f][bq + 3];
    *(float4*)&xTh[(((size_t)tl * NSL + e) * IN_DIM + (i0 + f)) * SW + bl] = v;
  }
}

// ---------------------------------------------------------------------------
// Fused LCN+LIF layer (round-7 structure, deeper MLP inner loop).
// hsrc: [nt][8][dprev][16], memout: [nt][8][dim][16], state: [2][8][dim][16].
// ONE neuron-group per block, t-inner; idx/w hoisted once. blockIdx%8 =
// slice = XCD (grid <= residency: LB(128,4) -> 8 blk/CU -> 2048 >= all
// grids, so round-robin pinning is exact). Inner loop: 8/8/9 chunked batch
// loads into alternating reg buffers so ~8-16 float4 gathers stay in
// flight while FMAs of the previous chunk retire (round-7 was ~4).
// ---------------------------------------------------------------------------
template <int NT>
__global__ __launch_bounds__(128, 4) void lcn_fused(
    const float* __restrict__ hsrc, const float* __restrict__ w,
    const float* __restrict__ bias, const int* __restrict__ knn,
    float* __restrict__ memout, float* __restrict__ state,
    int dim, int dprev, int load_state, int save_state) {
  const int e  = blockIdx.x & 7;          // slice -> XCD
  const int g  = blockIdx.x >> 3;         // neuron group
  const int nl = threadIdx.x >> 2;        // neuron in group (0..31)
  const int bq = (threadIdx.x & 3) * 4;   // batch quad within slice
  const int dd = g * NPG + nl;
  const bool act = dd < dim;
  const int d  = act ? dd : dim - 1;      // clamped for loads

  int   idx[K];
  float wr[K];
#pragma unroll
  for (int k = 0; k < K; ++k) {
    idx[k] = knn[d * K + k] * SW + bq;
    wr[k]  = w[d * K + k];
  }
  const float bi = bias[d];

  float4 sy = make_float4(0.f, 0.f, 0.f, 0.f);
  float4 me = make_float4(0.f, 0.f, 0.f, 0.f);
  if (load_state) {
    const size_t so = ((size_t)e * dim + d) * SW + bq;
    sy = *(const float4*)&state[so];
    me = *(const float4*)&state[(size_t)NSL * dim * SW + so];
  }

  for (int t = 0; t < NT; ++t) {
    const float* hp = hsrc + ((size_t)t * NSL + e) * dprev * SW;
    float4 ha[9], hb[8];
    // chunk0 loads (k=0..7)
#pragma unroll
    for (int j = 0; j < 8; ++j) ha[j] = *(const float4*)&hp[idx[j]];
    // chunk1 loads (k=8..15) issue while chunk0 FMAs retire
#pragma unroll
    for (int j = 0; j < 8; ++j) hb[j] = *(const float4*)&hp[idx[8 + j]];
    float4 a0 = make_float4(bi, bi, bi, bi);
    float4 a1 = make_float4(0.f, 0.f, 0.f, 0.f);
#pragma unroll
    for (int j = 0; j < 8; ++j) {
      const float wk = wr[j];
      if (j & 1) {
        a1.x = fmaf(wk, ha[j].x, a1.x);
        a1.y = fmaf(wk, ha[j].y, a1.y);
        a1.z = fmaf(wk, ha[j].z, a1.z);
        a1.w = fmaf(wk, ha[j].w, a1.w);
      } else {
        a0.x = fmaf(wk, ha[j].x, a0.x);
        a0.y = fmaf(wk, ha[j].y, a0.y);
        a0.z = fmaf(wk, ha[j].z, a0.z);
        a0.w = fmaf(wk, ha[j].w, a0.w);
      }
    }
    // chunk2 loads (k=16..24) issue while chunk1 FMAs retire
#pragma unroll
    for (int j = 0; j < 9; ++j) ha[j] = *(const float4*)&hp[idx[16 + j]];
#pragma unroll
    for (int j = 0; j < 8; ++j) {
      const float wk = wr[8 + j];
      if (j & 1) {
        a1.x = fmaf(wk, hb[j].x, a1.x);
        a1.y = fmaf(wk, hb[j].y, a1.y);
        a1.z = fmaf(wk, hb[j].z, a1.z);
        a1.w = fmaf(wk, hb[j].w, a1.w);
      } else {
        a0.x = fmaf(wk, hb[j].x, a0.x);
        a0.y = fmaf(wk, hb[j].y, a0.y);
        a0.z = fmaf(wk, hb[j].z, a0.z);
        a0.w = fmaf(wk, hb[j].w, a0.w);
      }
    }
#pragma unroll
    for (int j = 0; j < 9; ++j) {
      const float wk = wr[16 + j];
      if (j & 1) {
        a1.x = fmaf(wk, ha[j].x, a1.x);
        a1.y = fmaf(wk, ha[j].y, a1.y);
        a1.z = fmaf(wk, ha[j].z, a1.z);
        a1.w = fmaf(wk, ha[j].w, a1.w);
      } else {
        a0.x = fmaf(wk, ha[j].x, a0.x);
        a0.y = fmaf(wk, ha[j].y, a0.y);
        a0.z = fmaf(wk, ha[j].z, a0.z);
        a0.w = fmaf(wk, ha[j].w, a0.w);
      }
    }
    const float4 acc = make_float4(a0.x + a1.x, a0.y + a1.y, a0.z + a1.z,
                                   a0.w + a1.w);
    sy.x = ALPHA * sy.x + acc.x;
    sy.y = ALPHA * sy.y + acc.y;
    sy.z = ALPHA * sy.z + acc.z;
    sy.w = ALPHA * sy.w + acc.w;
    float4 r;
    r.x = (me.x > 1.0f) ? 1.0f : 0.0f;  // reset from PREVIOUS membrane
    r.y = (me.y > 1.0f) ? 1.0f : 0.0f;
    r.z = (me.z > 1.0f) ? 1.0f : 0.0f;
    r.w = (me.w > 1.0f) ? 1.0f : 0.0f;
    me.x = BETA * me.x + sy.x - r.x;
    me.y = BETA * me.y + sy.y - r.y;
    me.z = BETA * me.z + sy.z - r.z;
    me.w = BETA * me.w + sy.w - r.w;
    if (act) {
      *(float4*)&memout[(((size_t)t * NSL + e) * dim + d) * SW + bq] = me;
    }
  }

  if (save_state && act) {
    const size_t so = ((size_t)e * dim + d) * SW + bq;
    *(float4*)&state[so] = sy;
    *(float4*)&state[(size_t)NSL * dim * SW + so] = me;
  }
}

// Final FC on last timestep's layer-4 membrane: mem4_t15 [8][450][16].
__global__ __launch_bounds__(128) void fc_kernel(
    const float* __restrict__ mem4_t15, const float* __restrict__ fc_w,
    const float* __restrict__ fc_b, float* __restrict__ out) {
  const int b  = threadIdx.x;
  const int e  = b >> 4;
  const int bl = b & 15;
  float a0 = fc_b[0], a1 = fc_b[1];
  for (int d = 0; d < 450; ++d) {
    const float h = mem4_t15[((size_t)e * 450 + d) * SW + bl];
    a0 += fc_w[d] * h;
    a1 += fc_w[450 + d] * h;
  }
  out[b * 2 + 0] = a0;
  out[b * 2 + 1] = a1;
}

extern "C" void kernel_launch(void* const* d_in, const int* in_sizes, int n_in,
                              void* d_out, int out_size, void* d_ws,
                              size_t ws_size, hipStream_t stream) {
  (void)in_sizes; (void)n_in; (void)out_size; (void)ws_size;
  const float* x = (const float*)d_in[0];
  const float* w[5];
  const float* bias[5];
  const int* knn[5];
  for (int i = 0; i < 5; ++i) {
    w[i]    = (const float*)d_in[1 + 3 * i];
    bias[i] = (const float*)d_in[2 + 3 * i];
    knn[i]  = (const int*)d_in[3 + 3 * i];
  }
  const float* fc_w = (const float*)d_in[16];
  const float* fc_b = (const float*)d_in[17];
  float* out = (float*)d_out;

  static const int DIMS[5] = {7200, 3600, 1800, 900, 450};

  // Workspace (floats), 125.3 MB, slice-major [t][8][d][16]:
  //   A  : 16*8*7200*16 = 14,745,600   (mem0 -> mem2 -> mem4)
  //   XB : 8*8*14400*16 = 14,745,600   (xT half-slab; later mem1 + mem3)
  //   S  : 2*8*7200*16  =  1,843,200   (layer-0 syn/mem carry)
  float* A  = (float*)d_ws;
  float* XB = A + 14745600;
  float* S  = XB + 14745600;

  float* mem0 = A;
  float* mem1 = XB;
  float* mem2 = A;
  float* mem3 = XB + 7372800;
  float* mem4 = A;

  // ---- Layer 0 in two 8-t stages (xT half-slab reuse) ----
  for (int stage = 0; stage < 2; ++stage) {
    const int t0 = stage * 8;
    transpose_x4_kernel<<<dim3(IN_DIM / 64, B / 64, 8), 256, 0, stream>>>(
        x, XB, t0);
    const int ng = (DIMS[0] + NPG - 1) / NPG;  // 225
    lcn_fused<8><<<ng * NSL, 128, 0, stream>>>(
        XB, w[0], bias[0], knn[0], mem0 + (size_t)t0 * NSL * DIMS[0] * SW, S,
        DIMS[0], IN_DIM, /*load=*/stage, /*save=*/stage == 0);
  }

  // ---- Layers 1..4, all 16 timesteps ----
  const float* src = mem0;
  float* dsts[4] = {mem1, mem2, mem3, mem4};
  for (int i = 1; i < 5; ++i) {
    const int ng = (DIMS[i] + NPG - 1) / NPG;
    lcn_fused<16><<<ng * NSL, 128, 0, stream>>>(
        src, w[i], bias[i], knn[i], dsts[i - 1], nullptr, DIMS[i],
        DIMS[i - 1], 0, 0);
    src = dsts[i - 1];
  }

  fc_kernel<<<1, 128, 0, stream>>>(mem4 + (size_t)15 * NSL * DIMS[4] * SW,
                                   fc_w, fc_b, out);
}